// Round 2
// baseline (283.049 us; speedup 1.0000x reference)
//
#include <hip/hip_runtime.h>
#include <math.h>

// Problem constants
#define Bb   2
#define Cc   64
#define Nn   131072L        // D*H*W = 32*64*64
#define CN   (64L * 131072L)
#define Kk   8

// ws float layout:
// [0,256)      ctx[b*128 + a*64 + c]   a=0: mean(x_lf), a=1: mean(x_hf)
// [256,384)    w_lf[b*64+c]
// [384,512)    w_hf[b*64+c]
// [512,1024)   tokT_sf[c*8+k]  = tokens[k,c] * C^-0.5
// [1024,1536)  GsT[o*8+k]      = scale * G[k,o]
// [1536,1600)  bv[o]

__global__ __launch_bounds__(256) void k_means(const float* __restrict__ xhf,
                                               const float* __restrict__ xlf,
                                               float* __restrict__ ws) {
    int j = blockIdx.x;                 // [0,256): b*128 + a*64 + c
    int b = j >> 7, a = (j >> 6) & 1, c = j & 63;
    const float* src = (a ? xhf : xlf) + ((long)(b * 64 + c)) * Nn;
    const float4* s4 = (const float4*)src;
    float sum = 0.f;
    for (int i = threadIdx.x; i < (int)(Nn / 4); i += 256) {
        float4 v = s4[i];
        sum += (v.x + v.y) + (v.z + v.w);
    }
    #pragma unroll
    for (int off = 32; off; off >>= 1) sum += __shfl_down(sum, off, 64);
    __shared__ float tmp[4];
    int lane = threadIdx.x & 63, wv = threadIdx.x >> 6;
    if (lane == 0) tmp[wv] = sum;
    __syncthreads();
    if (threadIdx.x == 0) {
        float t = (tmp[0] + tmp[1]) + (tmp[2] + tmp[3]);
        ws[j] = t * (1.0f / (float)Nn);
    }
}

__global__ __launch_bounds__(256) void k_pre(
    const float* __restrict__ tokens, const float* __restrict__ W_t2f,
    const float* __restrict__ b_t2f, const float* __restrict__ W_delta,
    const float* __restrict__ b_delta, const float* __restrict__ scale_p,
    const float* __restrict__ W_gate, const float* __restrict__ b_gate,
    const float* __restrict__ W_shared, const float* __restrict__ W_glf,
    const float* __restrict__ W_ghf, float* __restrict__ ws) {
    __shared__ float sh[2][16];
    __shared__ float tokt[8][64];
    __shared__ float mm[8][64];
    int tid = threadIdx.x;
    float scale = scale_p[0];

    // stage A: SE MLP layer 1 (ctx -> relu(ctx @ W_shared^T)), 32 outputs
    if (tid < 32) {
        int b = tid >> 4, r = tid & 15;
        float s = 0.f;
        for (int jj = 0; jj < 128; ++jj) s += ws[b * 128 + jj] * W_shared[r * 128 + jj];
        sh[b][r] = s > 0.f ? s : 0.f;
    }
    // stage C: tok_t[k][c] = tokens @ W_t2f^T + b_t2f ; also tokens*sf transposed
    for (int idx = tid; idx < 512; idx += 256) {
        int k = idx >> 6, c = idx & 63;
        float s = b_t2f[c];
        for (int cc = 0; cc < 64; ++cc) s += tokens[k * 64 + cc] * W_t2f[c * 64 + cc];
        tokt[k][c] = s;
        ws[512 + c * 8 + k] = tokens[k * 64 + c] * 0.125f;   // sf = 64^-0.5
    }
    __syncthreads();
    // stage B: gate weights w_lf/w_hf = 2*sigmoid(sh @ W^T)
    {
        int which = tid >> 7;            // 0: lf, 1: hf
        int b = (tid >> 6) & 1, c = tid & 63;
        const float* Wg = which ? W_ghf : W_glf;
        float s = 0.f;
        for (int r = 0; r < 16; ++r) s += sh[b][r] * Wg[c * 16 + r];
        float w = 2.f / (1.f + __expf(-s));
        ws[256 + which * 128 + b * 64 + c] = w;
    }
    // stage D: M[k][c] = tok_t @ W_delta^T
    for (int idx = tid; idx < 512; idx += 256) {
        int k = idx >> 6, c = idx & 63;
        float s = 0.f;
        for (int cc = 0; cc < 64; ++cc) s += tokt[k][cc] * W_delta[c * 64 + cc];
        mm[k][c] = s;
    }
    __syncthreads();
    // stage E: GsT[o][k] = scale * (M @ W_gate^T)[k][o] ; bv[o]
    for (int idx = tid; idx < 512; idx += 256) {
        int o = idx >> 3, k = idx & 7;
        float s = 0.f;
        for (int cc = 0; cc < 64; ++cc) s += mm[k][cc] * W_gate[o * 64 + cc];
        ws[1024 + o * 8 + k] = scale * s;
    }
    if (tid < 64) {
        float s = 0.f;
        for (int cc = 0; cc < 64; ++cc) s += b_delta[cc] * W_gate[tid * 64 + cc];
        ws[1536 + tid] = scale * s + b_gate[tid];
    }
}

__global__ __launch_bounds__(256, 2) void k_main(
    const float* __restrict__ xhf, const float* __restrict__ xlf,
    const float* __restrict__ ws, float* __restrict__ out) {
    __shared__ float tokT[64][8];
    __shared__ float GT[64][8];
    __shared__ float wlf[64], whf[64], bvs[64];
    int tid = threadIdx.x;
    int b = blockIdx.x >> 9;             // 512 blocks per batch
    {
        float* t0 = &tokT[0][0];
        t0[tid]       = ws[512 + tid];
        t0[256 + tid] = ws[768 + tid];
        float* g0 = &GT[0][0];
        g0[tid]       = ws[1024 + tid];
        g0[256 + tid] = ws[1280 + tid];
        if (tid < 64) {
            wlf[tid] = ws[256 + b * 64 + tid];
            whf[tid] = ws[384 + b * 64 + tid];
            bvs[tid] = ws[1536 + tid];
        }
    }
    __syncthreads();

    long n = ((long)(blockIdx.x & 511)) * 256 + tid;
    const float* ph = xhf + (long)b * CN + n;
    const float* pl = xlf + (long)b * CN + n;

    float xh[64], xl[64];
    #pragma unroll
    for (int c = 0; c < 64; ++c) {
        xh[c] = ph[(long)c * Nn];
        xl[c] = pl[(long)c * Nn];
    }

    float lg[8];
    #pragma unroll
    for (int k = 0; k < 8; ++k) lg[k] = 0.f;
    #pragma unroll
    for (int c = 0; c < 64; ++c) {
        float s = xh[c] + xl[c];
        #pragma unroll
        for (int k = 0; k < 8; ++k) lg[k] += s * tokT[c][k];
    }

    float m = lg[0];
    #pragma unroll
    for (int k = 1; k < 8; ++k) m = fmaxf(m, lg[k]);
    float a[8];
    float den = 0.f;
    #pragma unroll
    for (int k = 0; k < 8; ++k) { a[k] = __expf(lg[k] - m); den += a[k]; }
    float rden = 1.f / den;
    #pragma unroll
    for (int k = 0; k < 8; ++k) a[k] *= rden;

    float* po = out + (long)b * CN + n;
    #pragma unroll
    for (int o = 0; o < 64; ++o) {
        float gp = bvs[o];
        #pragma unroll
        for (int k = 0; k < 8; ++k) gp += a[k] * GT[o][k];
        float g = 1.f / (1.f + __expf(-gp));
        float base = wlf[o] * xl[o] + whf[o] * xh[o];
        po[(long)o * Nn] = base * (1.f + g);
    }
}

extern "C" void kernel_launch(void* const* d_in, const int* in_sizes, int n_in,
                              void* d_out, int out_size, void* d_ws, size_t ws_size,
                              hipStream_t stream) {
    const float* xhf      = (const float*)d_in[0];
    const float* xlf      = (const float*)d_in[1];
    const float* tokens   = (const float*)d_in[2];
    const float* W_t2f    = (const float*)d_in[3];
    const float* b_t2f    = (const float*)d_in[4];
    const float* W_delta  = (const float*)d_in[5];
    const float* b_delta  = (const float*)d_in[6];
    const float* scale    = (const float*)d_in[7];
    const float* W_gate   = (const float*)d_in[8];
    const float* b_gate   = (const float*)d_in[9];
    const float* W_shared = (const float*)d_in[10];
    const float* W_glf    = (const float*)d_in[11];
    const float* W_ghf    = (const float*)d_in[12];
    float* ws  = (float*)d_ws;
    float* out = (float*)d_out;

    hipLaunchKernelGGL(k_means, dim3(256), dim3(256), 0, stream, xhf, xlf, ws);
    hipLaunchKernelGGL(k_pre, dim3(1), dim3(256), 0, stream,
                       tokens, W_t2f, b_t2f, W_delta, b_delta, scale,
                       W_gate, b_gate, W_shared, W_glf, W_ghf, ws);
    hipLaunchKernelGGL(k_main, dim3(1024), dim3(256), 0, stream, xhf, xlf, ws, out);
}

// Round 3
// 237.168 us; speedup vs baseline: 1.1935x; 1.1935x over previous
//
#include <hip/hip_runtime.h>
#include <math.h>

// Problem constants
#define Bb   2
#define Cc   64
#define Nn   131072L        // D*H*W = 32*64*64
#define CN   (64L * 131072L)
#define Kk   8
#define PARTS 8             // partial blocks per (b,a,c) slice

// ws float layout:
// [256,384)    w_lf[b*64+c]
// [384,512)    w_hf[b*64+c]
// [512,1024)   tokT_sf[c*8+k]  = tokens[k,c] * C^-0.5
// [1024,1536)  GsT[o*8+k]      = scale * G[k,o]
// [1536,1600)  bv[o]
// [2048,4096)  partial sums: ws[2048 + j*8 + p], j = b*128+a*64+c

__global__ __launch_bounds__(256) void k_means(const float* __restrict__ xhf,
                                               const float* __restrict__ xlf,
                                               float* __restrict__ ws) {
    int j = blockIdx.x >> 3;            // [0,256): b*128 + a*64 + c
    int p = blockIdx.x & 7;
    int b = j >> 7, a = (j >> 6) & 1, c = j & 63;
    const float* src = (a ? xhf : xlf) + ((long)(b * 64 + c)) * Nn + (long)p * (Nn / PARTS);
    const float4* s4 = (const float4*)src;
    float sum = 0.f;
    #pragma unroll 4
    for (int i = threadIdx.x; i < (int)(Nn / PARTS / 4); i += 256) {
        float4 v = s4[i];
        sum += (v.x + v.y) + (v.z + v.w);
    }
    #pragma unroll
    for (int off = 32; off; off >>= 1) sum += __shfl_down(sum, off, 64);
    __shared__ float tmp[4];
    int lane = threadIdx.x & 63, wv = threadIdx.x >> 6;
    if (lane == 0) tmp[wv] = sum;
    __syncthreads();
    if (threadIdx.x == 0) {
        ws[2048 + j * 8 + p] = (tmp[0] + tmp[1]) + (tmp[2] + tmp[3]);
    }
}

__global__ __launch_bounds__(256) void k_pre(
    const float* __restrict__ tokens, const float* __restrict__ W_t2f,
    const float* __restrict__ b_t2f, const float* __restrict__ W_delta,
    const float* __restrict__ b_delta, const float* __restrict__ scale_p,
    const float* __restrict__ W_gate, const float* __restrict__ b_gate,
    const float* __restrict__ W_shared, const float* __restrict__ W_glf,
    const float* __restrict__ W_ghf, float* __restrict__ ws) {
    __shared__ float ctx[256];
    __shared__ float sh[2][16];
    __shared__ float tokt[8][64];
    __shared__ float mm[8][64];
    int tid = threadIdx.x;
    float scale = scale_p[0];

    // stage 0: reduce 8 partials per slice -> ctx
    {
        float s = 0.f;
        #pragma unroll
        for (int p = 0; p < 8; ++p) s += ws[2048 + tid * 8 + p];
        ctx[tid] = s * (1.0f / (float)Nn);
    }
    __syncthreads();

    // stage A: SE MLP layer 1 (ctx -> relu(ctx @ W_shared^T)), 32 outputs
    if (tid < 32) {
        int b = tid >> 4, r = tid & 15;
        const float4* wrow = (const float4*)(W_shared + r * 128);
        const float4* crow = (const float4*)(ctx + b * 128);
        float s = 0.f;
        #pragma unroll
        for (int jj = 0; jj < 32; ++jj) {
            float4 wv = wrow[jj], cv = crow[jj];
            s += wv.x * cv.x + wv.y * cv.y + wv.z * cv.z + wv.w * cv.w;
        }
        sh[b][r] = s > 0.f ? s : 0.f;
    }
    // stage C: tok_t[k][c] = tokens @ W_t2f^T + b_t2f ; also tokens*sf transposed
    for (int idx = tid; idx < 512; idx += 256) {
        int k = idx >> 6, c = idx & 63;
        const float4* trow = (const float4*)(tokens + k * 64);
        const float4* wrow = (const float4*)(W_t2f + c * 64);
        float s = b_t2f[c];
        #pragma unroll
        for (int cc = 0; cc < 16; ++cc) {
            float4 tv = trow[cc], wv = wrow[cc];
            s += tv.x * wv.x + tv.y * wv.y + tv.z * wv.z + tv.w * wv.w;
        }
        tokt[k][c] = s;
        ws[512 + c * 8 + k] = tokens[k * 64 + c] * 0.125f;   // sf = 64^-0.5
    }
    __syncthreads();
    // stage B: gate weights w_lf/w_hf = 2*sigmoid(sh @ W^T)
    {
        int which = tid >> 7;            // 0: lf, 1: hf
        int b = (tid >> 6) & 1, c = tid & 63;
        const float* Wg = which ? W_ghf : W_glf;
        float s = 0.f;
        #pragma unroll
        for (int r = 0; r < 16; ++r) s += sh[b][r] * Wg[c * 16 + r];
        float w = 2.f / (1.f + __expf(-s));
        ws[256 + which * 128 + b * 64 + c] = w;
    }
    // stage D: M[k][c] = tok_t @ W_delta^T
    for (int idx = tid; idx < 512; idx += 256) {
        int k = idx >> 6, c = idx & 63;
        const float4* mrow = (const float4*)(&tokt[k][0]);
        const float4* wrow = (const float4*)(W_delta + c * 64);
        float s = 0.f;
        #pragma unroll
        for (int cc = 0; cc < 16; ++cc) {
            float4 tv = mrow[cc], wv = wrow[cc];
            s += tv.x * wv.x + tv.y * wv.y + tv.z * wv.z + tv.w * wv.w;
        }
        mm[k][c] = s;
    }
    __syncthreads();
    // stage E: GsT[o][k] = scale * (M @ W_gate^T)[k][o] ; bv[o]
    for (int idx = tid; idx < 512; idx += 256) {
        int o = idx >> 3, k = idx & 7;
        const float4* mrow = (const float4*)(&mm[k][0]);
        const float4* wrow = (const float4*)(W_gate + o * 64);
        float s = 0.f;
        #pragma unroll
        for (int cc = 0; cc < 16; ++cc) {
            float4 tv = mrow[cc], wv = wrow[cc];
            s += tv.x * wv.x + tv.y * wv.y + tv.z * wv.z + tv.w * wv.w;
        }
        ws[1024 + o * 8 + k] = scale * s;
    }
    if (tid < 64) {
        const float4* brow = (const float4*)(b_delta);
        const float4* wrow = (const float4*)(W_gate + tid * 64);
        float s = 0.f;
        #pragma unroll
        for (int cc = 0; cc < 16; ++cc) {
            float4 tv = brow[cc], wv = wrow[cc];
            s += tv.x * wv.x + tv.y * wv.y + tv.z * wv.z + tv.w * wv.w;
        }
        ws[1536 + tid] = scale * s + b_gate[tid];
    }
}

__global__ __launch_bounds__(256, 2) void k_main(
    const float* __restrict__ xhf, const float* __restrict__ xlf,
    const float* __restrict__ ws, float* __restrict__ out) {
    __shared__ float tokT[64][8];
    __shared__ float GT[64][8];
    __shared__ float wlf[64], whf[64], bvs[64];
    int tid = threadIdx.x;
    int b = blockIdx.x >> 9;             // 512 blocks per batch
    {
        float* t0 = &tokT[0][0];
        t0[tid]       = ws[512 + tid];
        t0[256 + tid] = ws[768 + tid];
        float* g0 = &GT[0][0];
        g0[tid]       = ws[1024 + tid];
        g0[256 + tid] = ws[1280 + tid];
        if (tid < 64) {
            wlf[tid] = ws[256 + b * 64 + tid];
            whf[tid] = ws[384 + b * 64 + tid];
            bvs[tid] = ws[1536 + tid];
        }
    }
    __syncthreads();

    long n = ((long)(blockIdx.x & 511)) * 256 + tid;
    const float* ph = xhf + (long)b * CN + n;
    const float* pl = xlf + (long)b * CN + n;

    float xh[64], xl[64];
    #pragma unroll
    for (int c = 0; c < 64; ++c) {
        xh[c] = ph[(long)c * Nn];
        xl[c] = pl[(long)c * Nn];
    }

    float lg[8];
    #pragma unroll
    for (int k = 0; k < 8; ++k) lg[k] = 0.f;
    #pragma unroll
    for (int c = 0; c < 64; ++c) {
        float s = xh[c] + xl[c];
        #pragma unroll
        for (int k = 0; k < 8; ++k) lg[k] += s * tokT[c][k];
    }

    float m = lg[0];
    #pragma unroll
    for (int k = 1; k < 8; ++k) m = fmaxf(m, lg[k]);
    float a[8];
    float den = 0.f;
    #pragma unroll
    for (int k = 0; k < 8; ++k) { a[k] = __expf(lg[k] - m); den += a[k]; }
    float rden = 1.f / den;
    #pragma unroll
    for (int k = 0; k < 8; ++k) a[k] *= rden;

    float* po = out + (long)b * CN + n;
    #pragma unroll
    for (int o = 0; o < 64; ++o) {
        float gp = bvs[o];
        #pragma unroll
        for (int k = 0; k < 8; ++k) gp += a[k] * GT[o][k];
        float g = 1.f / (1.f + __expf(-gp));
        float base = wlf[o] * xl[o] + whf[o] * xh[o];
        __builtin_nontemporal_store(base * (1.f + g), &po[(long)o * Nn]);
    }
}

extern "C" void kernel_launch(void* const* d_in, const int* in_sizes, int n_in,
                              void* d_out, int out_size, void* d_ws, size_t ws_size,
                              hipStream_t stream) {
    const float* xhf      = (const float*)d_in[0];
    const float* xlf      = (const float*)d_in[1];
    const float* tokens   = (const float*)d_in[2];
    const float* W_t2f    = (const float*)d_in[3];
    const float* b_t2f    = (const float*)d_in[4];
    const float* W_delta  = (const float*)d_in[5];
    const float* b_delta  = (const float*)d_in[6];
    const float* scale    = (const float*)d_in[7];
    const float* W_gate   = (const float*)d_in[8];
    const float* b_gate   = (const float*)d_in[9];
    const float* W_shared = (const float*)d_in[10];
    const float* W_glf    = (const float*)d_in[11];
    const float* W_ghf    = (const float*)d_in[12];
    float* ws  = (float*)d_ws;
    float* out = (float*)d_out;

    hipLaunchKernelGGL(k_means, dim3(2048), dim3(256), 0, stream, xhf, xlf, ws);
    hipLaunchKernelGGL(k_pre, dim3(1), dim3(256), 0, stream,
                       tokens, W_t2f, b_t2f, W_delta, b_delta, scale,
                       W_gate, b_gate, W_shared, W_glf, W_ghf, ws);
    hipLaunchKernelGGL(k_main, dim3(1024), dim3(256), 0, stream, xhf, xlf, ws, out);
}

// Round 4
// 232.484 us; speedup vs baseline: 1.2175x; 1.0201x over previous
//
#include <hip/hip_runtime.h>
#include <math.h>

// Problem constants
#define Bb   2
#define Cc   64
#define Nn   131072L        // D*H*W = 32*64*64
#define CN   (64L * 131072L)
#define Kk   8
#define PARTS 8             // partial blocks per (b,a,c) slice

// ws float layout:
// [256,384)    w_lf[b*64+c]
// [384,512)    w_hf[b*64+c]
// [512,1024)   tokT_sf[c*8+k]  = tokens[k,c] * C^-0.5
// [1024,1536)  GsT[o*8+k]      = scale * G[k,o]
// [1536,1600)  bv[o]
// [2048,4096)  partial sums: ws[2048 + j*8 + p], j = b*128+a*64+c

__global__ __launch_bounds__(256) void k_means(
    const float* __restrict__ xhf, const float* __restrict__ xlf,
    const float* __restrict__ tokens, const float* __restrict__ W_t2f,
    const float* __restrict__ b_t2f, const float* __restrict__ W_delta,
    const float* __restrict__ b_delta, const float* __restrict__ scale_p,
    const float* __restrict__ W_gate, const float* __restrict__ b_gate,
    float* __restrict__ ws) {
    int tid = threadIdx.x;
    if (blockIdx.x < 2048) {
        // --- streaming partial-sum blocks ---
        int j = blockIdx.x >> 3;            // [0,256): b*128 + a*64 + c
        int p = blockIdx.x & 7;
        int b = j >> 7, a = (j >> 6) & 1, c = j & 63;
        const float* src = (a ? xhf : xlf) + ((long)(b * 64 + c)) * Nn + (long)p * (Nn / PARTS);
        const float4* s4 = (const float4*)src;
        // 16 float4 loads, fully unrolled, 4 independent accumulators
        float4 a0 = {0.f, 0.f, 0.f, 0.f}, a1 = a0, a2 = a0, a3 = a0;
        #pragma unroll
        for (int i = 0; i < 16; i += 4) {
            float4 v0 = s4[(i + 0) * 256 + tid];
            float4 v1 = s4[(i + 1) * 256 + tid];
            float4 v2 = s4[(i + 2) * 256 + tid];
            float4 v3 = s4[(i + 3) * 256 + tid];
            a0.x += v0.x; a0.y += v0.y; a0.z += v0.z; a0.w += v0.w;
            a1.x += v1.x; a1.y += v1.y; a1.z += v1.z; a1.w += v1.w;
            a2.x += v2.x; a2.y += v2.y; a2.z += v2.z; a2.w += v2.w;
            a3.x += v3.x; a3.y += v3.y; a3.z += v3.z; a3.w += v3.w;
        }
        float sum = ((a0.x + a0.y) + (a0.z + a0.w)) + ((a1.x + a1.y) + (a1.z + a1.w))
                  + ((a2.x + a2.y) + (a2.z + a2.w)) + ((a3.x + a3.y) + (a3.z + a3.w));
        #pragma unroll
        for (int off = 32; off; off >>= 1) sum += __shfl_down(sum, off, 64);
        __shared__ float tmp[4];
        int lane = tid & 63, wv = tid >> 6;
        if (lane == 0) tmp[wv] = sum;
        __syncthreads();
        if (tid == 0) ws[2048 + j * 8 + p] = (tmp[0] + tmp[1]) + (tmp[2] + tmp[3]);
    } else {
        // --- token chain block (independent of the means) ---
        __shared__ float tokt[8][64];
        __shared__ float mm[8][64];
        float scale = scale_p[0];
        // stage C: tok_t = tokens @ W_t2f^T + b_t2f ; also tokens*sf transposed
        for (int idx = tid; idx < 512; idx += 256) {
            int k = idx >> 6, c = idx & 63;
            const float4* trow = (const float4*)(tokens + k * 64);
            const float4* wrow = (const float4*)(W_t2f + c * 64);
            float s = b_t2f[c];
            #pragma unroll
            for (int cc = 0; cc < 16; ++cc) {
                float4 tv = trow[cc], wv = wrow[cc];
                s += tv.x * wv.x + tv.y * wv.y + tv.z * wv.z + tv.w * wv.w;
            }
            tokt[k][c] = s;
            ws[512 + c * 8 + k] = tokens[k * 64 + c] * 0.125f;   // sf = 64^-0.5
        }
        __syncthreads();
        // stage D: M = tok_t @ W_delta^T
        for (int idx = tid; idx < 512; idx += 256) {
            int k = idx >> 6, c = idx & 63;
            const float4* mrow = (const float4*)(&tokt[k][0]);
            const float4* wrow = (const float4*)(W_delta + c * 64);
            float s = 0.f;
            #pragma unroll
            for (int cc = 0; cc < 16; ++cc) {
                float4 tv = mrow[cc], wv = wrow[cc];
                s += tv.x * wv.x + tv.y * wv.y + tv.z * wv.z + tv.w * wv.w;
            }
            mm[k][c] = s;
        }
        __syncthreads();
        // stage E: GsT[o][k] = scale*(M @ W_gate^T)[k][o] ; bv[o]
        for (int idx = tid; idx < 512; idx += 256) {
            int o = idx >> 3, k = idx & 7;
            const float4* mrow = (const float4*)(&mm[k][0]);
            const float4* wrow = (const float4*)(W_gate + o * 64);
            float s = 0.f;
            #pragma unroll
            for (int cc = 0; cc < 16; ++cc) {
                float4 tv = mrow[cc], wv = wrow[cc];
                s += tv.x * wv.x + tv.y * wv.y + tv.z * wv.z + tv.w * wv.w;
            }
            ws[1024 + o * 8 + k] = scale * s;
        }
        if (tid < 64) {
            const float4* brow = (const float4*)(b_delta);
            const float4* wrow = (const float4*)(W_gate + tid * 64);
            float s = 0.f;
            #pragma unroll
            for (int cc = 0; cc < 16; ++cc) {
                float4 tv = brow[cc], wv = wrow[cc];
                s += tv.x * wv.x + tv.y * wv.y + tv.z * wv.z + tv.w * wv.w;
            }
            ws[1536 + tid] = scale * s + b_gate[tid];
        }
    }
}

__global__ __launch_bounds__(256) void k_pre(
    const float* __restrict__ W_shared, const float* __restrict__ W_glf,
    const float* __restrict__ W_ghf, float* __restrict__ ws) {
    __shared__ float ctx[256];
    __shared__ float sh[2][16];
    int tid = threadIdx.x;
    // stage 0: reduce 8 partials per slice -> ctx
    {
        float s = 0.f;
        #pragma unroll
        for (int p = 0; p < 8; ++p) s += ws[2048 + tid * 8 + p];
        ctx[tid] = s * (1.0f / (float)Nn);
    }
    __syncthreads();
    // stage A: SE MLP layer 1
    if (tid < 32) {
        int b = tid >> 4, r = tid & 15;
        const float4* wrow = (const float4*)(W_shared + r * 128);
        const float4* crow = (const float4*)(ctx + b * 128);
        float s = 0.f;
        #pragma unroll
        for (int jj = 0; jj < 32; ++jj) {
            float4 wv = wrow[jj], cv = crow[jj];
            s += wv.x * cv.x + wv.y * cv.y + wv.z * cv.z + wv.w * cv.w;
        }
        sh[b][r] = s > 0.f ? s : 0.f;
    }
    __syncthreads();
    // stage B: w_lf/w_hf = 2*sigmoid(sh @ W^T)
    {
        int which = tid >> 7;            // 0: lf, 1: hf
        int b = (tid >> 6) & 1, c = tid & 63;
        const float* Wg = which ? W_ghf : W_glf;
        float s = 0.f;
        #pragma unroll
        for (int r = 0; r < 16; ++r) s += sh[b][r] * Wg[c * 16 + r];
        float w = 2.f / (1.f + __expf(-s));
        ws[256 + which * 128 + b * 64 + c] = w;
    }
}

__global__ __launch_bounds__(256, 2) void k_main(
    const float* __restrict__ xhf, const float* __restrict__ xlf,
    const float* __restrict__ ws, float* __restrict__ out) {
    __shared__ float tokT[64][8];
    __shared__ float GT[64][8];
    __shared__ float wlf[64], whf[64], bvs[64];
    int tid = threadIdx.x;
    int b = blockIdx.x >> 9;             // 512 blocks per batch
    {
        float* t0 = &tokT[0][0];
        t0[tid]       = ws[512 + tid];
        t0[256 + tid] = ws[768 + tid];
        float* g0 = &GT[0][0];
        g0[tid]       = ws[1024 + tid];
        g0[256 + tid] = ws[1280 + tid];
        if (tid < 64) {
            wlf[tid] = ws[256 + b * 64 + tid];
            whf[tid] = ws[384 + b * 64 + tid];
            bvs[tid] = ws[1536 + tid];
        }
    }
    __syncthreads();

    long n = ((long)(blockIdx.x & 511)) * 256 + tid;
    const float* ph = xhf + (long)b * CN + n;
    const float* pl = xlf + (long)b * CN + n;

    float xh[64], xl[64];
    #pragma unroll
    for (int c = 0; c < 64; ++c) {
        xh[c] = ph[(long)c * Nn];
        xl[c] = pl[(long)c * Nn];
    }

    float lg[8];
    #pragma unroll
    for (int k = 0; k < 8; ++k) lg[k] = 0.f;
    #pragma unroll
    for (int c = 0; c < 64; ++c) {
        float s = xh[c] + xl[c];
        #pragma unroll
        for (int k = 0; k < 8; ++k) lg[k] += s * tokT[c][k];
    }

    float m = lg[0];
    #pragma unroll
    for (int k = 1; k < 8; ++k) m = fmaxf(m, lg[k]);
    float a[8];
    float den = 0.f;
    #pragma unroll
    for (int k = 0; k < 8; ++k) { a[k] = __expf(lg[k] - m); den += a[k]; }
    float rden = 1.f / den;
    #pragma unroll
    for (int k = 0; k < 8; ++k) a[k] *= rden;

    float* po = out + (long)b * CN + n;
    #pragma unroll
    for (int o = 0; o < 64; ++o) {
        float gp = bvs[o];
        #pragma unroll
        for (int k = 0; k < 8; ++k) gp += a[k] * GT[o][k];
        float g = 1.f / (1.f + __expf(-gp));
        float base = wlf[o] * xl[o] + whf[o] * xh[o];
        __builtin_nontemporal_store(base * (1.f + g), &po[(long)o * Nn]);
    }
}

extern "C" void kernel_launch(void* const* d_in, const int* in_sizes, int n_in,
                              void* d_out, int out_size, void* d_ws, size_t ws_size,
                              hipStream_t stream) {
    const float* xhf      = (const float*)d_in[0];
    const float* xlf      = (const float*)d_in[1];
    const float* tokens   = (const float*)d_in[2];
    const float* W_t2f    = (const float*)d_in[3];
    const float* b_t2f    = (const float*)d_in[4];
    const float* W_delta  = (const float*)d_in[5];
    const float* b_delta  = (const float*)d_in[6];
    const float* scale    = (const float*)d_in[7];
    const float* W_gate   = (const float*)d_in[8];
    const float* b_gate   = (const float*)d_in[9];
    const float* W_shared = (const float*)d_in[10];
    const float* W_glf    = (const float*)d_in[11];
    const float* W_ghf    = (const float*)d_in[12];
    float* ws  = (float*)d_ws;
    float* out = (float*)d_out;

    hipLaunchKernelGGL(k_means, dim3(2049), dim3(256), 0, stream,
                       xhf, xlf, tokens, W_t2f, b_t2f, W_delta, b_delta, scale,
                       W_gate, b_gate, ws);
    hipLaunchKernelGGL(k_pre, dim3(1), dim3(256), 0, stream,
                       W_shared, W_glf, W_ghf, ws);
    hipLaunchKernelGGL(k_main, dim3(1024), dim3(256), 0, stream, xhf, xlf, ws, out);
}

// Round 8
// 232.421 us; speedup vs baseline: 1.2178x; 1.0003x over previous
//
#include <hip/hip_runtime.h>
#include <math.h>

// Problem constants
#define Bb   2
#define Cc   64
#define Nn   131072L        // D*H*W = 32*64*64
#define CN   (64L * 131072L)
#define Kk   8
#define PARTS 16            // partial blocks per (b,a,c) slice

// ws float layout:
// [256,384)    w_lf[b*64+c]
// [384,512)    w_hf[b*64+c]
// [512,1024)   tokT_sf[c*8+k]  = tokens[k,c] * C^-0.5
// [1024,1536)  GsT[o*8+k]      = scale * G[k,o]
// [1536,1600)  bv[o]
// [2048,6144)  partial sums: ws[2048 + j*16 + p], j = b*128+a*64+c

__global__ __launch_bounds__(256) void k_means(const float* __restrict__ xhf,
                                               const float* __restrict__ xlf,
                                               float* __restrict__ ws) {
    int tid = threadIdx.x;
    int j = blockIdx.x >> 4;            // [0,256): b*128 + a*64 + c
    int p = blockIdx.x & 15;
    int b = j >> 7, a = (j >> 6) & 1, c = j & 63;
    const float* src = (a ? xhf : xlf) + ((long)(b * 64 + c)) * Nn + (long)p * (Nn / PARTS);
    const float4* s4 = (const float4*)src;
    // 8 float4 loads per thread, all resident simultaneously (32 data VGPRs)
    float4 v0 = s4[0 * 256 + tid];
    float4 v1 = s4[1 * 256 + tid];
    float4 v2 = s4[2 * 256 + tid];
    float4 v3 = s4[3 * 256 + tid];
    float4 v4 = s4[4 * 256 + tid];
    float4 v5 = s4[5 * 256 + tid];
    float4 v6 = s4[6 * 256 + tid];
    float4 v7 = s4[7 * 256 + tid];
    float s0 = (v0.x + v0.y) + (v0.z + v0.w);
    float s1 = (v1.x + v1.y) + (v1.z + v1.w);
    float s2 = (v2.x + v2.y) + (v2.z + v2.w);
    float s3 = (v3.x + v3.y) + (v3.z + v3.w);
    float s4s = (v4.x + v4.y) + (v4.z + v4.w);
    float s5 = (v5.x + v5.y) + (v5.z + v5.w);
    float s6 = (v6.x + v6.y) + (v6.z + v6.w);
    float s7 = (v7.x + v7.y) + (v7.z + v7.w);
    float sum = ((s0 + s1) + (s2 + s3)) + ((s4s + s5) + (s6 + s7));
    #pragma unroll
    for (int off = 32; off; off >>= 1) sum += __shfl_down(sum, off, 64);
    __shared__ float tmp[4];
    int lane = tid & 63, wv = tid >> 6;
    if (lane == 0) tmp[wv] = sum;
    __syncthreads();
    if (tid == 0) ws[2048 + j * 16 + p] = (tmp[0] + tmp[1]) + (tmp[2] + tmp[3]);
}

__global__ __launch_bounds__(256) void k_pre(
    const float* __restrict__ tokens, const float* __restrict__ W_t2f,
    const float* __restrict__ b_t2f, const float* __restrict__ W_delta,
    const float* __restrict__ b_delta, const float* __restrict__ scale_p,
    const float* __restrict__ W_gate, const float* __restrict__ b_gate,
    const float* __restrict__ W_shared, const float* __restrict__ W_glf,
    const float* __restrict__ W_ghf, float* __restrict__ ws) {
    __shared__ float ctx[256];
    __shared__ float sh[2][16];
    __shared__ float tokt[8][64];
    __shared__ float mm[8][64];
    int tid = threadIdx.x;
    float scale = scale_p[0];

    // stage 0: reduce 16 partials per slice -> ctx
    {
        float s = 0.f;
        #pragma unroll
        for (int p = 0; p < 16; ++p) s += ws[2048 + tid * 16 + p];
        ctx[tid] = s * (1.0f / (float)Nn);
    }
    __syncthreads();

    // stage A: SE MLP layer 1 (ctx -> relu(ctx @ W_shared^T)), 32 outputs
    if (tid < 32) {
        int b = tid >> 4, r = tid & 15;
        const float4* wrow = (const float4*)(W_shared + r * 128);
        const float4* crow = (const float4*)(ctx + b * 128);
        float s = 0.f;
        #pragma unroll
        for (int jj = 0; jj < 32; ++jj) {
            float4 wv = wrow[jj], cv = crow[jj];
            s += wv.x * cv.x + wv.y * cv.y + wv.z * cv.z + wv.w * cv.w;
        }
        sh[b][r] = s > 0.f ? s : 0.f;
    }
    // stage C: tok_t[k][c] = tokens @ W_t2f^T + b_t2f ; also tokens*sf transposed
    for (int idx = tid; idx < 512; idx += 256) {
        int k = idx >> 6, c = idx & 63;
        const float4* trow = (const float4*)(tokens + k * 64);
        const float4* wrow = (const float4*)(W_t2f + c * 64);
        float s = b_t2f[c];
        #pragma unroll
        for (int cc = 0; cc < 16; ++cc) {
            float4 tv = trow[cc], wv = wrow[cc];
            s += tv.x * wv.x + tv.y * wv.y + tv.z * wv.z + tv.w * wv.w;
        }
        tokt[k][c] = s;
        ws[512 + c * 8 + k] = tokens[k * 64 + c] * 0.125f;   // sf = 64^-0.5
    }
    __syncthreads();
    // stage B: gate weights w_lf/w_hf = 2*sigmoid(sh @ W^T)
    {
        int which = tid >> 7;            // 0: lf, 1: hf
        int b = (tid >> 6) & 1, c = tid & 63;
        const float* Wg = which ? W_ghf : W_glf;
        float s = 0.f;
        #pragma unroll
        for (int r = 0; r < 16; ++r) s += sh[b][r] * Wg[c * 16 + r];
        float w = 2.f / (1.f + __expf(-s));
        ws[256 + which * 128 + b * 64 + c] = w;
    }
    // stage D: M[k][c] = tok_t @ W_delta^T
    for (int idx = tid; idx < 512; idx += 256) {
        int k = idx >> 6, c = idx & 63;
        const float4* mrow = (const float4*)(&tokt[k][0]);
        const float4* wrow = (const float4*)(W_delta + c * 64);
        float s = 0.f;
        #pragma unroll
        for (int cc = 0; cc < 16; ++cc) {
            float4 tv = mrow[cc], wv = wrow[cc];
            s += tv.x * wv.x + tv.y * wv.y + tv.z * wv.z + tv.w * wv.w;
        }
        mm[k][c] = s;
    }
    __syncthreads();
    // stage E: GsT[o][k] = scale * (M @ W_gate^T)[k][o] ; bv[o]
    for (int idx = tid; idx < 512; idx += 256) {
        int o = idx >> 3, k = idx & 7;
        const float4* mrow = (const float4*)(&mm[k][0]);
        const float4* wrow = (const float4*)(W_gate + o * 64);
        float s = 0.f;
        #pragma unroll
        for (int cc = 0; cc < 16; ++cc) {
            float4 tv = mrow[cc], wv = wrow[cc];
            s += tv.x * wv.x + tv.y * wv.y + tv.z * wv.z + tv.w * wv.w;
        }
        ws[1024 + o * 8 + k] = scale * s;
    }
    if (tid < 64) {
        const float4* brow = (const float4*)(b_delta);
        const float4* wrow = (const float4*)(W_gate + tid * 64);
        float s = 0.f;
        #pragma unroll
        for (int cc = 0; cc < 16; ++cc) {
            float4 tv = brow[cc], wv = wrow[cc];
            s += tv.x * wv.x + tv.y * wv.y + tv.z * wv.z + tv.w * wv.w;
        }
        ws[1536 + tid] = scale * s + b_gate[tid];
    }
}

__global__ __launch_bounds__(256, 2) void k_main(
    const float* __restrict__ xhf, const float* __restrict__ xlf,
    const float* __restrict__ ws, float* __restrict__ out) {
    __shared__ float tokT[64][8];
    __shared__ float GT[64][8];
    __shared__ float wlf[64], whf[64], bvs[64];
    int tid = threadIdx.x;
    int b = blockIdx.x >> 9;             // 512 blocks per batch
    {
        float* t0 = &tokT[0][0];
        t0[tid]       = ws[512 + tid];
        t0[256 + tid] = ws[768 + tid];
        float* g0 = &GT[0][0];
        g0[tid]       = ws[1024 + tid];
        g0[256 + tid] = ws[1280 + tid];
        if (tid < 64) {
            wlf[tid] = ws[256 + b * 64 + tid];
            whf[tid] = ws[384 + b * 64 + tid];
            bvs[tid] = ws[1536 + tid];
        }
    }
    __syncthreads();

    long n = ((long)(blockIdx.x & 511)) * 256 + tid;
    const float* ph = xhf + (long)b * CN + n;
    const float* pl = xlf + (long)b * CN + n;

    float xh[64], xl[64];
    #pragma unroll
    for (int c = 0; c < 64; ++c) {
        xh[c] = ph[(long)c * Nn];
        xl[c] = pl[(long)c * Nn];
    }

    float lg[8];
    #pragma unroll
    for (int k = 0; k < 8; ++k) lg[k] = 0.f;
    #pragma unroll
    for (int c = 0; c < 64; ++c) {
        float s = xh[c] + xl[c];
        #pragma unroll
        for (int k = 0; k < 8; ++k) lg[k] += s * tokT[c][k];
    }

    float m = lg[0];
    #pragma unroll
    for (int k = 1; k < 8; ++k) m = fmaxf(m, lg[k]);
    float a[8];
    float den = 0.f;
    #pragma unroll
    for (int k = 0; k < 8; ++k) { a[k] = __expf(lg[k] - m); den += a[k]; }
    float rden = 1.f / den;
    #pragma unroll
    for (int k = 0; k < 8; ++k) a[k] *= rden;

    float* po = out + (long)b * CN + n;
    #pragma unroll
    for (int o = 0; o < 64; ++o) {
        float gp = bvs[o];
        #pragma unroll
        for (int k = 0; k < 8; ++k) gp += a[k] * GT[o][k];
        float g = 1.f / (1.f + __expf(-gp));
        float base = wlf[o] * xl[o] + whf[o] * xh[o];
        __builtin_nontemporal_store(base * (1.f + g), &po[(long)o * Nn]);
    }
}

extern "C" void kernel_launch(void* const* d_in, const int* in_sizes, int n_in,
                              void* d_out, int out_size, void* d_ws, size_t ws_size,
                              hipStream_t stream) {
    const float* xhf      = (const float*)d_in[0];
    const float* xlf      = (const float*)d_in[1];
    const float* tokens   = (const float*)d_in[2];
    const float* W_t2f    = (const float*)d_in[3];
    const float* b_t2f    = (const float*)d_in[4];
    const float* W_delta  = (const float*)d_in[5];
    const float* b_delta  = (const float*)d_in[6];
    const float* scale    = (const float*)d_in[7];
    const float* W_gate   = (const float*)d_in[8];
    const float* b_gate   = (const float*)d_in[9];
    const float* W_shared = (const float*)d_in[10];
    const float* W_glf    = (const float*)d_in[11];
    const float* W_ghf    = (const float*)d_in[12];
    float* ws  = (float*)d_ws;
    float* out = (float*)d_out;

    hipLaunchKernelGGL(k_means, dim3(4096), dim3(256), 0, stream, xhf, xlf, ws);
    hipLaunchKernelGGL(k_pre, dim3(1), dim3(256), 0, stream,
                       tokens, W_t2f, b_t2f, W_delta, b_delta, scale,
                       W_gate, b_gate, W_shared, W_glf, W_ghf, ws);
    hipLaunchKernelGGL(k_main, dim3(1024), dim3(256), 0, stream, xhf, xlf, ws, out);
}

// Round 11
// 227.877 us; speedup vs baseline: 1.2421x; 1.0199x over previous
//
#include <hip/hip_runtime.h>
#include <math.h>

// Problem constants
#define Bb   2
#define Cc   64
#define Nn   131072L        // D*H*W = 32*64*64
#define CN   (64L * 131072L)
#define Kk   8
#define PARTS 8             // partial blocks per (b,a,c) slice

// ws float layout:
// [256,384)    w_lf[b*64+c]
// [384,512)    w_hf[b*64+c]
// [512,1024)   tokT_sf[c*8+k]  = tokens[k,c] * C^-0.5
// [1024,1536)  GsT[o*8+k]      = scale * G[k,o]
// [1536,1600)  bv[o]
// [2048,4096)  partial sums: ws[2048 + j*8 + p], j = b*128+a*64+c

__global__ __launch_bounds__(256) void k_means(const float* __restrict__ xhf,
                                               const float* __restrict__ xlf,
                                               float* __restrict__ ws) {
    int tid = threadIdx.x;
    int j = blockIdx.x >> 3;            // [0,256): b*128 + a*64 + c
    int p = blockIdx.x & 7;
    int b = j >> 7, a = (j >> 6) & 1, c = j & 63;
    const float* src = (a ? xhf : xlf) + ((long)(b * 64 + c)) * Nn + (long)p * (Nn / PARTS);
    const float4* s4 = (const float4*)src + tid;
    // 16 float4 loads per thread, all resident simultaneously (64 data VGPRs)
    float4 v[16];
    #pragma unroll
    for (int i = 0; i < 16; ++i) v[i] = s4[i * 256];
    float ps[16];
    #pragma unroll
    for (int i = 0; i < 16; ++i) ps[i] = (v[i].x + v[i].y) + (v[i].z + v[i].w);
    #pragma unroll
    for (int st = 8; st; st >>= 1) {
        #pragma unroll
        for (int i = 0; i < 8; ++i) if (i < st) ps[i] += ps[i + st];
    }
    float sum = ps[0];
    #pragma unroll
    for (int off = 32; off; off >>= 1) sum += __shfl_down(sum, off, 64);
    __shared__ float tmp[4];
    int lane = tid & 63, wv = tid >> 6;
    if (lane == 0) tmp[wv] = sum;
    __syncthreads();
    if (tid == 0) ws[2048 + j * 8 + p] = (tmp[0] + tmp[1]) + (tmp[2] + tmp[3]);
}

__global__ __launch_bounds__(256) void k_pre(
    const float* __restrict__ tokens, const float* __restrict__ W_t2f,
    const float* __restrict__ b_t2f, const float* __restrict__ W_delta,
    const float* __restrict__ b_delta, const float* __restrict__ scale_p,
    const float* __restrict__ W_gate, const float* __restrict__ b_gate,
    const float* __restrict__ W_shared, const float* __restrict__ W_glf,
    const float* __restrict__ W_ghf, float* __restrict__ ws) {
    __shared__ float ctx[256];
    __shared__ float sh[2][16];
    __shared__ float tokt[8][64];
    __shared__ float mm[8][64];
    int tid = threadIdx.x;
    float scale = scale_p[0];

    // stage 0: reduce 8 partials per slice -> ctx
    {
        float s = 0.f;
        #pragma unroll
        for (int p = 0; p < 8; ++p) s += ws[2048 + tid * 8 + p];
        ctx[tid] = s * (1.0f / (float)Nn);
    }
    __syncthreads();

    // stage A: SE MLP layer 1 (ctx -> relu(ctx @ W_shared^T)), 32 outputs
    if (tid < 32) {
        int b = tid >> 4, r = tid & 15;
        const float4* wrow = (const float4*)(W_shared + r * 128);
        const float4* crow = (const float4*)(ctx + b * 128);
        float s = 0.f;
        #pragma unroll
        for (int jj = 0; jj < 32; ++jj) {
            float4 wv = wrow[jj], cv = crow[jj];
            s += wv.x * cv.x + wv.y * cv.y + wv.z * cv.z + wv.w * cv.w;
        }
        sh[b][r] = s > 0.f ? s : 0.f;
    }
    // stage C: tok_t[k][c] = tokens @ W_t2f^T + b_t2f ; also tokens*sf transposed
    for (int idx = tid; idx < 512; idx += 256) {
        int k = idx >> 6, c = idx & 63;
        const float4* trow = (const float4*)(tokens + k * 64);
        const float4* wrow = (const float4*)(W_t2f + c * 64);
        float s = b_t2f[c];
        #pragma unroll
        for (int cc = 0; cc < 16; ++cc) {
            float4 tv = trow[cc], wv = wrow[cc];
            s += tv.x * wv.x + tv.y * wv.y + tv.z * wv.z + tv.w * wv.w;
        }
        tokt[k][c] = s;
        ws[512 + c * 8 + k] = tokens[k * 64 + c] * 0.125f;   // sf = 64^-0.5
    }
    __syncthreads();
    // stage B: gate weights w_lf/w_hf = 2*sigmoid(sh @ W^T)
    {
        int which = tid >> 7;            // 0: lf, 1: hf
        int b = (tid >> 6) & 1, c = tid & 63;
        const float* Wg = which ? W_ghf : W_glf;
        float s = 0.f;
        #pragma unroll
        for (int r = 0; r < 16; ++r) s += sh[b][r] * Wg[c * 16 + r];
        float w = 2.f / (1.f + __expf(-s));
        ws[256 + which * 128 + b * 64 + c] = w;
    }
    // stage D: M[k][c] = tok_t @ W_delta^T
    for (int idx = tid; idx < 512; idx += 256) {
        int k = idx >> 6, c = idx & 63;
        const float4* mrow = (const float4*)(&tokt[k][0]);
        const float4* wrow = (const float4*)(W_delta + c * 64);
        float s = 0.f;
        #pragma unroll
        for (int cc = 0; cc < 16; ++cc) {
            float4 tv = mrow[cc], wv = wrow[cc];
            s += tv.x * wv.x + tv.y * wv.y + tv.z * wv.z + tv.w * wv.w;
        }
        mm[k][c] = s;
    }
    __syncthreads();
    // stage E: GsT[o][k] = scale * (M @ W_gate^T)[k][o] ; bv[o]
    for (int idx = tid; idx < 512; idx += 256) {
        int o = idx >> 3, k = idx & 7;
        const float4* mrow = (const float4*)(&mm[k][0]);
        const float4* wrow = (const float4*)(W_gate + o * 64);
        float s = 0.f;
        #pragma unroll
        for (int cc = 0; cc < 16; ++cc) {
            float4 tv = mrow[cc], wv = wrow[cc];
            s += tv.x * wv.x + tv.y * wv.y + tv.z * wv.z + tv.w * wv.w;
        }
        ws[1024 + o * 8 + k] = scale * s;
    }
    if (tid < 64) {
        const float4* brow = (const float4*)(b_delta);
        const float4* wrow = (const float4*)(W_gate + tid * 64);
        float s = 0.f;
        #pragma unroll
        for (int cc = 0; cc < 16; ++cc) {
            float4 tv = brow[cc], wv = wrow[cc];
            s += tv.x * wv.x + tv.y * wv.y + tv.z * wv.z + tv.w * wv.w;
        }
        ws[1536 + tid] = scale * s + b_gate[tid];
    }
}

__global__ __launch_bounds__(256, 4) void k_main(
    const float* __restrict__ xhf, const float* __restrict__ xlf,
    const float* __restrict__ ws, float* __restrict__ out) {
    __shared__ float tokT[64][8];
    __shared__ float GT[64][8];
    __shared__ float wlf[64], whf[64], bvs[64];
    int tid = threadIdx.x;
    int b = blockIdx.x >> 9;             // 512 blocks per batch
    {
        float* t0 = &tokT[0][0];
        t0[tid]       = ws[512 + tid];
        t0[256 + tid] = ws[768 + tid];
        float* g0 = &GT[0][0];
        g0[tid]       = ws[1024 + tid];
        g0[256 + tid] = ws[1280 + tid];
        if (tid < 64) {
            wlf[tid] = ws[256 + b * 64 + tid];
            whf[tid] = ws[384 + b * 64 + tid];
            bvs[tid] = ws[1536 + tid];
        }
    }
    __syncthreads();

    long n = ((long)(blockIdx.x & 511)) * 256 + tid;
    const float* ph = xhf + (long)b * CN + n;
    const float* pl = xlf + (long)b * CN + n;

    // single pass: fold SE gate early (base in regs), accumulate logits
    float base[64];
    float lg[8];
    #pragma unroll
    for (int k = 0; k < 8; ++k) lg[k] = 0.f;
    #pragma unroll
    for (int c = 0; c < 64; ++c) {
        float xh = ph[(long)c * Nn];
        float xl = pl[(long)c * Nn];
        float s = xh + xl;
        #pragma unroll
        for (int k = 0; k < 8; ++k) lg[k] += s * tokT[c][k];
        base[c] = wlf[c] * xl + whf[c] * xh;
    }

    float m = lg[0];
    #pragma unroll
    for (int k = 1; k < 8; ++k) m = fmaxf(m, lg[k]);
    float a[8];
    float den = 0.f;
    #pragma unroll
    for (int k = 0; k < 8; ++k) { a[k] = __expf(lg[k] - m); den += a[k]; }
    float rden = 1.f / den;
    #pragma unroll
    for (int k = 0; k < 8; ++k) a[k] *= rden;

    float* po = out + (long)b * CN + n;
    #pragma unroll
    for (int o = 0; o < 64; ++o) {
        float gp = bvs[o];
        #pragma unroll
        for (int k = 0; k < 8; ++k) gp += a[k] * GT[o][k];
        float g = 1.f / (1.f + __expf(-gp));
        __builtin_nontemporal_store(base[o] * (1.f + g), &po[(long)o * Nn]);
    }
}

extern "C" void kernel_launch(void* const* d_in, const int* in_sizes, int n_in,
                              void* d_out, int out_size, void* d_ws, size_t ws_size,
                              hipStream_t stream) {
    const float* xhf      = (const float*)d_in[0];
    const float* xlf      = (const float*)d_in[1];
    const float* tokens   = (const float*)d_in[2];
    const float* W_t2f    = (const float*)d_in[3];
    const float* b_t2f    = (const float*)d_in[4];
    const float* W_delta  = (const float*)d_in[5];
    const float* b_delta  = (const float*)d_in[6];
    const float* scale    = (const float*)d_in[7];
    const float* W_gate   = (const float*)d_in[8];
    const float* b_gate   = (const float*)d_in[9];
    const float* W_shared = (const float*)d_in[10];
    const float* W_glf    = (const float*)d_in[11];
    const float* W_ghf    = (const float*)d_in[12];
    float* ws  = (float*)d_ws;
    float* out = (float*)d_out;

    hipLaunchKernelGGL(k_means, dim3(2048), dim3(256), 0, stream, xhf, xlf, ws);
    hipLaunchKernelGGL(k_pre, dim3(1), dim3(256), 0, stream,
                       tokens, W_t2f, b_t2f, W_delta, b_delta, scale,
                       W_gate, b_gate, W_shared, W_glf, W_ghf, ws);
    hipLaunchKernelGGL(k_main, dim3(1024), dim3(256), 0, stream, xhf, xlf, ws, out);
}

// Round 16
// 224.692 us; speedup vs baseline: 1.2597x; 1.0142x over previous
//
#include <hip/hip_runtime.h>
#include <math.h>

// Problem constants
#define Bb   2
#define Cc   64
#define Nn   131072L        // D*H*W = 32*64*64
#define CN   (64L * 131072L)
#define Kk   8
#define PARTS 16            // partial blocks per (b,a,c) slice

// ws float layout:
// [256,384)    w_lf[b*64+c]
// [384,512)    w_hf[b*64+c]
// [512,1024)   tokT_sf[c*8+k]  = tokens[k,c] * C^-0.5
// [1024,1536)  GsT[o*8+k]      = scale * G[k,o]
// [1536,1600)  bv[o]
// [2048,6144)  partial sums: ws[2048 + j*16 + p], j = b*128+a*64+c

__global__ __launch_bounds__(256) void k_means(const float* __restrict__ xhf,
                                               const float* __restrict__ xlf,
                                               float* __restrict__ ws) {
    int tid = threadIdx.x;
    int j = blockIdx.x >> 4;            // [0,256): b*128 + a*64 + c
    int p = blockIdx.x & 15;
    int b = j >> 7, a = (j >> 6) & 1, c = j & 63;
    const float* src = (a ? xhf : xlf) + ((long)(b * 64 + c)) * Nn + (long)p * (Nn / PARTS);
    const float4* s4 = (const float4*)src;
    // 8 float4 loads per thread, all resident simultaneously (32 data VGPRs)
    float4 v0 = s4[0 * 256 + tid];
    float4 v1 = s4[1 * 256 + tid];
    float4 v2 = s4[2 * 256 + tid];
    float4 v3 = s4[3 * 256 + tid];
    float4 v4 = s4[4 * 256 + tid];
    float4 v5 = s4[5 * 256 + tid];
    float4 v6 = s4[6 * 256 + tid];
    float4 v7 = s4[7 * 256 + tid];
    float s0 = (v0.x + v0.y) + (v0.z + v0.w);
    float s1 = (v1.x + v1.y) + (v1.z + v1.w);
    float s2 = (v2.x + v2.y) + (v2.z + v2.w);
    float s3 = (v3.x + v3.y) + (v3.z + v3.w);
    float s4s = (v4.x + v4.y) + (v4.z + v4.w);
    float s5 = (v5.x + v5.y) + (v5.z + v5.w);
    float s6 = (v6.x + v6.y) + (v6.z + v6.w);
    float s7 = (v7.x + v7.y) + (v7.z + v7.w);
    float sum = ((s0 + s1) + (s2 + s3)) + ((s4s + s5) + (s6 + s7));
    #pragma unroll
    for (int off = 32; off; off >>= 1) sum += __shfl_down(sum, off, 64);
    __shared__ float tmp[4];
    int lane = tid & 63, wv = tid >> 6;
    if (lane == 0) tmp[wv] = sum;
    __syncthreads();
    if (tid == 0) ws[2048 + j * 16 + p] = (tmp[0] + tmp[1]) + (tmp[2] + tmp[3]);
}

__global__ __launch_bounds__(256) void k_pre(
    const float* __restrict__ tokens, const float* __restrict__ W_t2f,
    const float* __restrict__ b_t2f, const float* __restrict__ W_delta,
    const float* __restrict__ b_delta, const float* __restrict__ scale_p,
    const float* __restrict__ W_gate, const float* __restrict__ b_gate,
    const float* __restrict__ W_shared, const float* __restrict__ W_glf,
    const float* __restrict__ W_ghf, float* __restrict__ ws) {
    __shared__ float ctx[256];
    __shared__ float sh[2][16];
    __shared__ float tokt[8][64];
    __shared__ float mm[8][64];
    int tid = threadIdx.x;
    float scale = scale_p[0];

    // stage 0: reduce 16 partials per slice -> ctx
    {
        float s = 0.f;
        #pragma unroll
        for (int p = 0; p < 16; ++p) s += ws[2048 + tid * 16 + p];
        ctx[tid] = s * (1.0f / (float)Nn);
    }
    __syncthreads();

    // stage A: SE MLP layer 1 (ctx -> relu(ctx @ W_shared^T)), 32 outputs
    if (tid < 32) {
        int b = tid >> 4, r = tid & 15;
        const float4* wrow = (const float4*)(W_shared + r * 128);
        const float4* crow = (const float4*)(ctx + b * 128);
        float s = 0.f;
        #pragma unroll
        for (int jj = 0; jj < 32; ++jj) {
            float4 wv = wrow[jj], cv = crow[jj];
            s += wv.x * cv.x + wv.y * cv.y + wv.z * cv.z + wv.w * cv.w;
        }
        sh[b][r] = s > 0.f ? s : 0.f;
    }
    // stage C: tok_t[k][c] = tokens @ W_t2f^T + b_t2f ; also tokens*sf transposed
    for (int idx = tid; idx < 512; idx += 256) {
        int k = idx >> 6, c = idx & 63;
        const float4* trow = (const float4*)(tokens + k * 64);
        const float4* wrow = (const float4*)(W_t2f + c * 64);
        float s = b_t2f[c];
        #pragma unroll
        for (int cc = 0; cc < 16; ++cc) {
            float4 tv = trow[cc], wv = wrow[cc];
            s += tv.x * wv.x + tv.y * wv.y + tv.z * wv.z + tv.w * wv.w;
        }
        tokt[k][c] = s;
        ws[512 + c * 8 + k] = tokens[k * 64 + c] * 0.125f;   // sf = 64^-0.5
    }
    __syncthreads();
    // stage B: gate weights w_lf/w_hf = 2*sigmoid(sh @ W^T)
    {
        int which = tid >> 7;            // 0: lf, 1: hf
        int b = (tid >> 6) & 1, c = tid & 63;
        const float* Wg = which ? W_ghf : W_glf;
        float s = 0.f;
        #pragma unroll
        for (int r = 0; r < 16; ++r) s += sh[b][r] * Wg[c * 16 + r];
        float w = 2.f / (1.f + __expf(-s));
        ws[256 + which * 128 + b * 64 + c] = w;
    }
    // stage D: M[k][c] = tok_t @ W_delta^T
    for (int idx = tid; idx < 512; idx += 256) {
        int k = idx >> 6, c = idx & 63;
        const float4* mrow = (const float4*)(&tokt[k][0]);
        const float4* wrow = (const float4*)(W_delta + c * 64);
        float s = 0.f;
        #pragma unroll
        for (int cc = 0; cc < 16; ++cc) {
            float4 tv = mrow[cc], wv = wrow[cc];
            s += tv.x * wv.x + tv.y * wv.y + tv.z * wv.z + tv.w * wv.w;
        }
        mm[k][c] = s;
    }
    __syncthreads();
    // stage E: GsT[o][k] = scale * (M @ W_gate^T)[k][o] ; bv[o]
    for (int idx = tid; idx < 512; idx += 256) {
        int o = idx >> 3, k = idx & 7;
        const float4* mrow = (const float4*)(&mm[k][0]);
        const float4* wrow = (const float4*)(W_gate + o * 64);
        float s = 0.f;
        #pragma unroll
        for (int cc = 0; cc < 16; ++cc) {
            float4 tv = mrow[cc], wv = wrow[cc];
            s += tv.x * wv.x + tv.y * wv.y + tv.z * wv.z + tv.w * wv.w;
        }
        ws[1024 + o * 8 + k] = scale * s;
    }
    if (tid < 64) {
        const float4* brow = (const float4*)(b_delta);
        const float4* wrow = (const float4*)(W_gate + tid * 64);
        float s = 0.f;
        #pragma unroll
        for (int cc = 0; cc < 16; ++cc) {
            float4 tv = brow[cc], wv = wrow[cc];
            s += tv.x * wv.x + tv.y * wv.y + tv.z * wv.z + tv.w * wv.w;
        }
        ws[1536 + tid] = scale * s + b_gate[tid];
    }
}

__global__ __launch_bounds__(256, 4) void k_main(
    const float* __restrict__ xhf, const float* __restrict__ xlf,
    const float* __restrict__ ws, float* __restrict__ out) {
    __shared__ float tokT[64][8];
    __shared__ float GT[64][8];
    __shared__ float wlf[64], whf[64], bvs[64];
    int tid = threadIdx.x;
    int b = blockIdx.x >> 9;             // 512 blocks per batch
    {
        float* t0 = &tokT[0][0];
        t0[tid]       = ws[512 + tid];
        t0[256 + tid] = ws[768 + tid];
        float* g0 = &GT[0][0];
        g0[tid]       = ws[1024 + tid];
        g0[256 + tid] = ws[1280 + tid];
        if (tid < 64) {
            wlf[tid] = ws[256 + b * 64 + tid];
            whf[tid] = ws[384 + b * 64 + tid];
            bvs[tid] = ws[1536 + tid];
        }
    }
    __syncthreads();

    long n = ((long)(blockIdx.x & 511)) * 256 + tid;
    const float* ph = xhf + (long)b * CN + n;
    const float* pl = xlf + (long)b * CN + n;

    // single pass: fold SE gate early (base in regs), accumulate logits
    float base[64];
    float lg[8];
    #pragma unroll
    for (int k = 0; k < 8; ++k) lg[k] = 0.f;
    #pragma unroll
    for (int c = 0; c < 64; ++c) {
        float xh = ph[(long)c * Nn];
        float xl = pl[(long)c * Nn];
        float s = xh + xl;
        #pragma unroll
        for (int k = 0; k < 8; ++k) lg[k] += s * tokT[c][k];
        base[c] = wlf[c] * xl + whf[c] * xh;
    }

    float m = lg[0];
    #pragma unroll
    for (int k = 1; k < 8; ++k) m = fmaxf(m, lg[k]);
    float a[8];
    float den = 0.f;
    #pragma unroll
    for (int k = 0; k < 8; ++k) { a[k] = __expf(lg[k] - m); den += a[k]; }
    float rden = 1.f / den;
    #pragma unroll
    for (int k = 0; k < 8; ++k) a[k] *= rden;

    float* po = out + (long)b * CN + n;
    #pragma unroll
    for (int o = 0; o < 64; ++o) {
        float gp = bvs[o];
        #pragma unroll
        for (int k = 0; k < 8; ++k) gp += a[k] * GT[o][k];
        float g = 1.f / (1.f + __expf(-gp));
        __builtin_nontemporal_store(base[o] * (1.f + g), &po[(long)o * Nn]);
    }
}

extern "C" void kernel_launch(void* const* d_in, const int* in_sizes, int n_in,
                              void* d_out, int out_size, void* d_ws, size_t ws_size,
                              hipStream_t stream) {
    const float* xhf      = (const float*)d_in[0];
    const float* xlf      = (const float*)d_in[1];
    const float* tokens   = (const float*)d_in[2];
    const float* W_t2f    = (const float*)d_in[3];
    const float* b_t2f    = (const float*)d_in[4];
    const float* W_delta  = (const float*)d_in[5];
    const float* b_delta  = (const float*)d_in[6];
    const float* scale    = (const float*)d_in[7];
    const float* W_gate   = (const float*)d_in[8];
    const float* b_gate   = (const float*)d_in[9];
    const float* W_shared = (const float*)d_in[10];
    const float* W_glf    = (const float*)d_in[11];
    const float* W_ghf    = (const float*)d_in[12];
    float* ws  = (float*)d_ws;
    float* out = (float*)d_out;

    hipLaunchKernelGGL(k_means, dim3(4096), dim3(256), 0, stream, xhf, xlf, ws);
    hipLaunchKernelGGL(k_pre, dim3(1), dim3(256), 0, stream,
                       tokens, W_t2f, b_t2f, W_delta, b_delta, scale,
                       W_gate, b_gate, W_shared, W_glf, W_ghf, ws);
    hipLaunchKernelGGL(k_main, dim3(1024), dim3(256), 0, stream, xhf, xlf, ws, out);
}